// Round 1
// baseline (467.696 us; speedup 1.0000x reference)
//
#include <hip/hip_runtime.h>
#include <math.h>

#define LMAX 8
#define EPB 128            // batch elements per block
#define TPB 512            // 8 waves
#define ESTRIDE 130        // padded elem dimension (128 + 2)
#define NCO 45             // sum_{l<=8}(l+1)
#define PLANE (NCO*ESTRIDE)
#define NRE 289            // max (2*l1+1)*(2*lo+1) record slots per entry
#define METAF 1024         // floats reserved at ws start for entry meta

typedef __attribute__((ext_vector_type(2))) float f32x2;

__host__ __device__ inline int tri_(int l){ return l*(l+1)/2; }

// Exact mirror of the reference FULL_MAP + POWER_MAP generation order.
// want==index -> fills L1,L2,LO,TY and returns; want==-1 -> returns count.
__host__ __device__ inline int entry_get(int want,int* L1,int* L2,int* LO,int* TY){
  int n=0;
#define EMIT(A,B,C,T) { if(n==(want)){*L1=(A);*L2=(B);*LO=(C);*TY=(T);return n;} n++; }
  for(int l1=0;l1<=LMAX;l1++)
    for(int l2=l1;l2<=LMAX;l2++){
      int hi = l1+l2; if(hi>LMAX) hi=LMAX;
      for(int lo=l2-l1;lo<=hi;lo++) EMIT(l1,l2,lo,0)
    }
  for(int l2=2;l2<=LMAX;l2++){ EMIT(1,l2,l2-1,1) if(l2>=4) EMIT(1,l2,l2,1) }
  for(int l2=3;l2<=LMAX;l2++){ EMIT(2,l2,l2-2,1) EMIT(2,l2,l2-1,1) }
  EMIT(3,3,2,1)
  for(int l2=4;l2<=LMAX;l2++){
    EMIT(3,l2,l2-3,1)
    if((l2&1)&&l2>=5){ EMIT(3,l2,l2-2,1) EMIT(3,l2,l2-1,1) }
  }
#undef EMIT
  return n;
}

// Clebsch-Gordan <j1 m1 j2 m2 | j3 m3>, Racah formula (double precision).
__device__ double cg_(int j1,int m1,int j2,int m2,int j3,int m3){
  if (m1+m2 != m3) return 0.0;
  int dj = j1-j2; if(dj<0) dj=-dj;
  if (j3 < dj || j3 > j1+j2) return 0.0;
  double f[26]; f[0]=1.0;
  for (int t=1;t<26;t++) f[t]=f[t-1]*(double)t;
  double pre = sqrt((2.0*j3+1.0)*f[j1+j2-j3]*f[j1-j2+j3]*f[-j1+j2+j3]/f[j1+j2+j3+1]);
  pre *= sqrt(f[j1+m1]*f[j1-m1]*f[j2+m2]*f[j2-m2]*f[j3+m3]*f[j3-m3]);
  int kmin = 0; if (j2-j3-m1>kmin) kmin=j2-j3-m1; if (j1-j3+m2>kmin) kmin=j1-j3+m2;
  int kmax = j1+j2-j3; if (j1-m1<kmax) kmax=j1-m1; if (j2+m2<kmax) kmax=j2+m2;
  double s=0.0;
  for (int k=kmin;k<=kmax;k++){
    double term = 1.0/(f[k]*f[j1+j2-j3-k]*f[j1-m1-k]*f[j2+m2-k]*f[j3-j2+m1+k]*f[j3-j1-m2+k]);
    s += (k&1)? -term : term;
  }
  return pre*s;
}

// Conjugate-reflection sign factors: F_l^{-m} = (-1)^m conj(F_l^m)  (m>=1)
// stored F'' = (r*Re_raw, q*Im_raw)
__device__ inline void sgn_(int m, float* r, float* q){
  if (m>=0){ *r=1.f; *q=1.f; }
  else { float s = ((-m)&1)? -1.f : 1.f; *r=s; *q=-s; }
}

// Build per-entry meta + dense (k,i) weight records {w1,w2,w3,w4} in d_ws.
// Gr += w1*(a*c) + w2*(b*d);  Gi += w3*(a*d) + w4*(b*c)
// with a,b = raw Re/Im of F1 at |m1|, c,d = raw Re/Im of F2 at |m2|.
__global__ void setup_kernel(float* __restrict__ ws){
  int e = blockIdx.x;
  int l1,l2,lo,ty;
  entry_get(e,&l1,&l2,&lo,&ty);
  if (threadIdx.x==0){
    int* meta=(int*)ws;
    meta[e*4+0]=l1; meta[e*4+1]=l2; meta[e*4+2]=lo; meta[e*4+3]=ty;
  }
  float* rec = ws + METAF + (size_t)e*(NRE*4);
  int ni = 2*l1+1, nk = 2*lo+1, tot = ni*nk;
  for (int t=threadIdx.x; t<tot; t+=blockDim.x){
    int k = t/ni, i = t-k*ni;
    int m1 = i-l1, M = k-lo, m2 = M-m1;
    float w1=0.f,w2=0.f,w3=0.f,w4=0.f;
    if (m2>=-l2 && m2<=l2){
      float C = (float)cg_(l1,m1,l2,m2,lo,M);
      float r1,q1,r2,q2; sgn_(m1,&r1,&q1); sgn_(m2,&r2,&q2);
      w1 =  C*r1*r2;
      w2 = -C*q1*q2;
      w3 =  C*r1*q2;
      w4 =  C*q1*r2;
    }
    rec[t*4+0]=w1; rec[t*4+1]=w2; rec[t*4+2]=w3; rec[t*4+3]=w4;
  }
}

template<int TL1, bool PRE>
__device__ __attribute__((always_inline)) void do_entry(
    const float* __restrict__ rec, const float* __restrict__ lds,
    int lane2, int l2, int lo, int ty,
    float* __restrict__ out, size_t outIdx, int NENT)
{
  const int NI = 2*TL1+1;
  const int B1 = (TL1*(TL1+1))/2;
  f32x2 F1r[NI], F1i[NI];
  if (PRE){
#pragma unroll
    for (int i=0;i<NI;i++){
      const int m1 = i-TL1; const int am = m1<0?-m1:m1;
      F1r[i] = *(const f32x2*)&lds[(B1+am)*ESTRIDE + lane2];
      F1i[i] = *(const f32x2*)&lds[PLANE + (B1+am)*ESTRIDE + lane2];
    }
  }
  f32x2 acc = (f32x2){0.f,0.f};
  const int b2 = tri_(l2), b3 = tri_(lo);
  for (int k=0;k<=2*lo;k++){
    const float* __restrict__ rk = rec + (size_t)k*NI*4;
    f32x2 Gr=(f32x2){0.f,0.f}, Gi=(f32x2){0.f,0.f};
    const int M = k-lo;
#pragma unroll
    for (int i=0;i<NI;i++){
      float w1=rk[i*4+0], w2=rk[i*4+1], w3=rk[i*4+2], w4=rk[i*4+3];
      int m2 = M-(i-TL1);
      int am2 = m2<0?-m2:m2; if (am2>l2) am2=l2;   // clamp; weights are 0 when invalid
      int o2 = (b2+am2)*ESTRIDE + lane2;
      f32x2 c2 = *(const f32x2*)&lds[o2];
      f32x2 d2 = *(const f32x2*)&lds[PLANE + o2];
      f32x2 av, bv;
      if (PRE){ av=F1r[i]; bv=F1i[i]; }
      else {
        const int m1 = i-TL1; const int am1 = m1<0?-m1:m1;
        av = *(const f32x2*)&lds[(B1+am1)*ESTRIDE + lane2];
        bv = *(const f32x2*)&lds[PLANE + (B1+am1)*ESTRIDE + lane2];
      }
      Gr = __builtin_elementwise_fma(av*c2, (f32x2){w1,w1}, Gr);
      Gr = __builtin_elementwise_fma(bv*d2, (f32x2){w2,w2}, Gr);
      Gi = __builtin_elementwise_fma(av*d2, (f32x2){w3,w3}, Gi);
      Gi = __builtin_elementwise_fma(bv*c2, (f32x2){w4,w4}, Gi);
    }
    if (ty==0){
      // beta_re += Re(G_k * conj(F_lo''_M)) ; F'' = (al*x, be*y) with raw x,y at |M|
      int aM = M<0?-M:M;
      int o3 = (b3+aM)*ESTRIDE + lane2;
      f32x2 xr = *(const f32x2*)&lds[o3];
      f32x2 yi = *(const f32x2*)&lds[PLANE + o3];
      float al, be;
      if (M>=0){ al=1.f; be=1.f; }
      else { float s=(aM&1)?-1.f:1.f; al=s; be=-s; }
      acc = __builtin_elementwise_fma(Gr*xr, (f32x2){al,al}, acc);
      acc = __builtin_elementwise_fma(Gi*yi, (f32x2){be,be}, acc);
    } else {
      acc = __builtin_elementwise_fma(Gr, Gr, acc);
      acc = __builtin_elementwise_fma(Gi, Gi, acc);
    }
  }
  out[outIdx] = acc.x;
  out[outIdx + NENT] = acc.y;   // second element of the lane's pair (next row)
}

__global__ __launch_bounds__(TPB, 4) void main_kernel(
    const float* __restrict__ re, const float* __restrict__ im,
    float* __restrict__ out, const float* __restrict__ ws, int NENT)
{
  __shared__ float lds[2*PLANE];
  const int gbase = blockIdx.x*EPB;
  // stage m<=l triangle of 128 elements into [coeff][elem] planes
  for (int t=threadIdx.x; t<EPB*81; t+=TPB){
    float vr = re[(size_t)gbase*81 + t];
    float vi = im[(size_t)gbase*81 + t];
    int elem = t/81, x = t-elem*81;
    int l = x/9, m = x-l*9;
    if (m<=l){
      int off = tri_(l)+m;
      lds[off*ESTRIDE+elem] = vr;
      lds[PLANE + off*ESTRIDE+elem] = vi;
    }
  }
  __syncthreads();

  const int lane  = threadIdx.x & 63;
  const int wv    = __builtin_amdgcn_readfirstlane(threadIdx.x >> 6);
  const int lane2 = lane*2;
  const int* meta = (const int*)ws;
  const size_t outIdx0 = (size_t)(gbase + lane2)*NENT;

  for (int e=wv; e<NENT; e+=8){
    int l1=meta[e*4+0], l2=meta[e*4+1], lo=meta[e*4+2], ty=meta[e*4+3];
    const float* rec = ws + METAF + (size_t)e*(NRE*4);
    size_t oi = outIdx0 + (size_t)e;
    switch(l1){
      case 0: do_entry<0,true >(rec,lds,lane2,l2,lo,ty,out,oi,NENT); break;
      case 1: do_entry<1,true >(rec,lds,lane2,l2,lo,ty,out,oi,NENT); break;
      case 2: do_entry<2,true >(rec,lds,lane2,l2,lo,ty,out,oi,NENT); break;
      case 3: do_entry<3,true >(rec,lds,lane2,l2,lo,ty,out,oi,NENT); break;
      case 4: do_entry<4,true >(rec,lds,lane2,l2,lo,ty,out,oi,NENT); break;
      case 5: do_entry<5,true >(rec,lds,lane2,l2,lo,ty,out,oi,NENT); break;
      case 6: do_entry<6,true >(rec,lds,lane2,l2,lo,ty,out,oi,NENT); break;
      case 7: do_entry<7,false>(rec,lds,lane2,l2,lo,ty,out,oi,NENT); break;
      default:do_entry<8,false>(rec,lds,lane2,l2,lo,ty,out,oi,NENT); break;
    }
  }
}

extern "C" void kernel_launch(void* const* d_in, const int* in_sizes, int n_in,
                              void* d_out, int out_size, void* d_ws, size_t ws_size,
                              hipStream_t stream) {
  const float* re = (const float*)d_in[0];
  const float* im = (const float*)d_in[1];
  float* out = (float*)d_out;
  float* ws  = (float*)d_ws;
  int a,b,c,t;
  const int NENT = entry_get(-1,&a,&b,&c,&t);       // 249
  const int batch = in_sizes[0] / 81;               // 65536
  setup_kernel<<<NENT, 256, 0, stream>>>(ws);
  main_kernel<<<batch/EPB, TPB, 0, stream>>>(re, im, out, ws, NENT);
}

// Round 3
// 430.141 us; speedup vs baseline: 1.0873x; 1.0873x over previous
//
#include <hip/hip_runtime.h>
#include <math.h>
#include <utility>

#define LMAX 8
#define NENT 249
#define EPB 128            // batch elements per block
#define TPB 256            // 4 waves
#define ESTRIDE 130        // padded elem dimension
#define NCO 45             // sum_{l<=8}(l+1)
#define PLANE (NCO*ESTRIDE)
#define NRE 289            // max (2*l1+1)*(2*lo+1) weight slots per entry

typedef __attribute__((ext_vector_type(2))) float f32x2;

struct Ent { int l1, l2, lo, ty; };

__host__ __device__ constexpr int tri_(int l){ return l*(l+1)/2; }

// Exact mirror of the reference FULL_MAP + POWER_MAP generation order.
__host__ __device__ constexpr Ent ent_of(int want){
  Ent r{0,0,0,0}; int n=0;
  for(int l1=0;l1<=LMAX;l1++)
    for(int l2=l1;l2<=LMAX;l2++){
      int hi=l1+l2; if(hi>LMAX)hi=LMAX;
      for(int lo=l2-l1;lo<=hi;lo++){ if(n==want){ r=Ent{l1,l2,lo,0}; } n++; }
    }
  for(int l2=2;l2<=LMAX;l2++){
    if(n==want) r=Ent{1,l2,l2-1,1}; n++;
    if(l2>=4){ if(n==want) r=Ent{1,l2,l2,1}; n++; }
  }
  for(int l2=3;l2<=LMAX;l2++){
    if(n==want) r=Ent{2,l2,l2-2,1}; n++;
    if(n==want) r=Ent{2,l2,l2-1,1}; n++;
  }
  if(n==want) r=Ent{3,3,2,1}; n++;
  for(int l2=4;l2<=LMAX;l2++){
    if(n==want) r=Ent{3,l2,l2-3,1}; n++;
    if((l2&1)&&l2>=5){
      if(n==want) r=Ent{3,l2,l2-2,1}; n++;
      if(n==want) r=Ent{3,l2,l2-1,1}; n++;
    }
  }
  return r;
}
__host__ __device__ constexpr int ent_count(){
  int n=0;
  for(int l1=0;l1<=LMAX;l1++)
    for(int l2=l1;l2<=LMAX;l2++){
      int hi=l1+l2; if(hi>LMAX)hi=LMAX;
      for(int lo=l2-l1;lo<=hi;lo++) n++;
    }
  for(int l2=2;l2<=LMAX;l2++){ n++; if(l2>=4) n++; }
  for(int l2=3;l2<=LMAX;l2++) n+=2;
  n++;
  for(int l2=4;l2<=LMAX;l2++){ n++; if((l2&1)&&l2>=5) n+=2; }
  return n;
}
static_assert(ent_count()==NENT, "entry count mismatch");

// Conjugate-reflection signs: F_l^{m} for m<0 equals ((-1)^|m| * Re, -(-1)^|m| * Im)
// of the stored value at |m|. r = real-part sign, q = imag-part sign.
__host__ __device__ constexpr int sr_(int m){ return m>=0 ? 1 : (((-m)&1)? -1 : 1); }
__host__ __device__ constexpr int sq_(int m){ return m>=0 ? 1 : (((-m)&1)? 1 : -1); }

// Clebsch-Gordan <j1 m1 j2 m2 | j3 m3>, Racah formula (double precision).
__device__ double cg_(int j1,int m1,int j2,int m2,int j3,int m3){
  if (m1+m2 != m3) return 0.0;
  int dj = j1-j2; if(dj<0) dj=-dj;
  if (j3 < dj || j3 > j1+j2) return 0.0;
  double f[26]; f[0]=1.0;
  for (int t=1;t<26;t++) f[t]=f[t-1]*(double)t;
  double pre = sqrt((2.0*j3+1.0)*f[j1+j2-j3]*f[j1-j2+j3]*f[-j1+j2+j3]/f[j1+j2+j3+1]);
  pre *= sqrt(f[j1+m1]*f[j1-m1]*f[j2+m2]*f[j2-m2]*f[j3+m3]*f[j3-m3]);
  int kmin = 0; if (j2-j3-m1>kmin) kmin=j2-j3-m1; if (j1-j3+m2>kmin) kmin=j1-j3+m2;
  int kmax = j1+j2-j3; if (j1-m1<kmax) kmax=j1-m1; if (j2+m2<kmax) kmax=j2+m2;
  double s=0.0;
  for (int k=kmin;k<=kmax;k++){
    double term = 1.0/(f[k]*f[j1+j2-j3-k]*f[j1-m1-k]*f[j2+m2-k]*f[j3-j2+m1+k]*f[j3-j1-m2+k]);
    s += (k&1)? -term : term;
  }
  return pre*s;
}

// ws layout: ws[e*NRE + k*(2*l1+1) + i] = plain CG coefficient C (0 if |m2|>l2).
__global__ void setup_kernel(float* __restrict__ ws){
  int e = blockIdx.x;
  Ent E = ent_of(e);
  int ni = 2*E.l1+1, nk = 2*E.lo+1, tot = ni*nk;
  int t = threadIdx.x;
  if (t < tot){
    int k = t/ni, i = t - k*ni;
    int m1 = i-E.l1, M = k-E.lo, m2 = M-m1;
    float C = 0.f;
    if (m2>=-E.l2 && m2<=E.l2) C = (float)cg_(E.l1,m1,E.l2,m2,E.lo,M);
    ws[(long long)e*NRE + t] = C;
  }
}

// Fully-unrolled per-entry compute. All indices/signs are compile-time after
// unroll; LDS reads use one base VGPR + immediate offsets; the compiler CSEs
// repeated F2 reads across the k-loop into registers.
template<int EE>
__device__ __attribute__((always_inline)) inline f32x2 proc_entry(
    const float* __restrict__ lds, const float* __restrict__ rec, int lane2)
{
  constexpr Ent E = ent_of(EE);
  constexpr int L1=E.l1, L2=E.l2, LO=E.lo, TY=E.ty;
  constexpr int NI = 2*L1+1;
  constexpr int B1 = tri_(L1), B2 = tri_(L2), B3 = tri_(LO);

  f32x2 F1r[NI], F1i[NI];
  if constexpr (L1 <= 5){
#pragma unroll
    for (int i=0;i<NI;i++){
      int am = i<L1 ? L1-i : i-L1;
      F1r[i] = *(const f32x2*)&lds[(B1+am)*ESTRIDE + lane2];
      F1i[i] = *(const f32x2*)&lds[PLANE + (B1+am)*ESTRIDE + lane2];
    }
  }

  f32x2 acc = {0.f, 0.f};
#pragma unroll
  for (int k=0;k<=2*LO;k++){
    const int M = k-LO;
    f32x2 Gr = {0.f,0.f}, Gi = {0.f,0.f};
#pragma unroll
    for (int i=0;i<NI;i++){
      const int m1 = i-L1;
      const int m2 = M-m1;
      const int am2 = m2<0? -m2:m2;
      if (am2 <= L2){                       // folds at compile time
        float C = rec[k*NI+i];              // wave-uniform -> s_load
        f32x2 c2 = *(const f32x2*)&lds[(B2+am2)*ESTRIDE + lane2];
        f32x2 d2 = *(const f32x2*)&lds[PLANE + (B2+am2)*ESTRIDE + lane2];
        f32x2 a, b;
        if constexpr (L1 <= 5){ a = F1r[i]; b = F1i[i]; }
        else {
          int am1 = m1<0? -m1:m1;
          a = *(const f32x2*)&lds[(B1+am1)*ESTRIDE + lane2];
          b = *(const f32x2*)&lds[PLANE + (B1+am1)*ESTRIDE + lane2];
        }
        const int r1=sr_(m1), q1=sq_(m1), r2=sr_(m2), q2=sq_(m2);
        const int s1=r1*r2, s2=-(q1*q2), s3=r1*q2, s4=q1*r2;
        // G += C * (F1*F2):  Gr += C(s1*a*c + s2*b*d); Gi += C(s3*a*d + s4*b*c)
        f32x2 t1 = (s1>0? a : -a) * c2;
        t1 = __builtin_elementwise_fma((s2>0? b : -b), d2, t1);
        f32x2 t2 = (s3>0? a : -a) * d2;
        t2 = __builtin_elementwise_fma((s4>0? b : -b), c2, t2);
        f32x2 Cv = {C, C};
        Gr = __builtin_elementwise_fma(Cv, t1, Gr);
        Gi = __builtin_elementwise_fma(Cv, t2, Gi);
      }
    }
    if constexpr (TY==0){
      const int aM = M<0? -M:M;
      f32x2 xr = *(const f32x2*)&lds[(B3+aM)*ESTRIDE + lane2];
      f32x2 yi = *(const f32x2*)&lds[PLANE + (B3+aM)*ESTRIDE + lane2];
      const int AL = sr_(M), BE = sq_(M);   // folds after unroll (NOT constexpr: M is a loop var)
      acc = __builtin_elementwise_fma(Gr, (AL>0? xr : -xr), acc);
      acc = __builtin_elementwise_fma(Gi, (BE>0? yi : -yi), acc);
    } else {
      acc = __builtin_elementwise_fma(Gr, Gr, acc);
      acc = __builtin_elementwise_fma(Gi, Gi, acc);
    }
  }
  return acc;
}

template<int EE>
__device__ __attribute__((always_inline)) inline void chain_step(
    const float* __restrict__ lds, const float* __restrict__ ws,
    float* __restrict__ out, int lane2, int s, int e_,
    long long baseA, f32x2* obuf)
{
  if (EE >= s && EE < e_){                  // wave-uniform branch
    obuf[EE & 7] = proc_entry<EE>(lds, ws + (long long)EE*NRE, lane2);
  }
  if constexpr (((EE & 7) == 7) || (EE == NENT-1)){
    constexpr int G8 = EE & ~7;
#pragma unroll
    for (int j=0; j <= (EE&7); j++){
      if (G8+j >= s && G8+j < e_){          // wave-uniform
        out[baseA + G8 + j]        = obuf[j].x;   // element A: 8 consecutive dwords/flush
        out[baseA + NENT + G8 + j] = obuf[j].y;   // element B
      }
    }
  }
}

template<int... Es>
__device__ __attribute__((always_inline)) inline void chain_all(
    std::integer_sequence<int, Es...>,
    const float* __restrict__ lds, const float* __restrict__ ws,
    float* __restrict__ out, int lane2, int s, int e_,
    long long baseA, f32x2* obuf)
{
  (chain_step<Es>(lds, ws, out, lane2, s, e_, baseA, obuf), ...);
}

__global__ __launch_bounds__(TPB, 3) void main_kernel(
    const float* __restrict__ re, const float* __restrict__ im,
    float* __restrict__ out, const float* __restrict__ ws, int4 bnd)
{
  __shared__ float lds[2*PLANE];
  const int gbase = blockIdx.x*EPB;
  for (int t=threadIdx.x; t<EPB*81; t+=TPB){
    float vr = re[(size_t)gbase*81 + t];
    float vi = im[(size_t)gbase*81 + t];
    int elem = t/81, x = t - elem*81;
    int l = x/9, m = x - l*9;
    if (m<=l){
      int off = tri_(l)+m;
      lds[off*ESTRIDE+elem] = vr;
      lds[PLANE + off*ESTRIDE+elem] = vi;
    }
  }
  __syncthreads();

  const int lane  = threadIdx.x & 63;
  const int wv    = __builtin_amdgcn_readfirstlane(threadIdx.x >> 6);
  const int lane2 = lane*2;
  const int s  = (wv==0)? 0     : (wv==1)? bnd.x : (wv==2)? bnd.y : bnd.z;
  const int e_ = (wv==0)? bnd.x : (wv==1)? bnd.y : (wv==2)? bnd.z : bnd.w;
  const long long baseA = (long long)(gbase + lane2)*NENT;

  f32x2 obuf[8];
#pragma unroll
  for (int j=0;j<8;j++) obuf[j] = f32x2{0.f,0.f};

  chain_all(std::make_integer_sequence<int, NENT>{},
            lds, ws, out, lane2, s, e_, baseA, obuf);
}

extern "C" void kernel_launch(void* const* d_in, const int* in_sizes, int n_in,
                              void* d_out, int out_size, void* d_ws, size_t ws_size,
                              hipStream_t stream) {
  const float* re = (const float*)d_in[0];
  const float* im = (const float*)d_in[1];
  float* out = (float*)d_out;
  float* ws  = (float*)d_ws;
  const int batch = in_sizes[0] / 81;

  // Host-side work-balanced contiguous entry ranges for the 4 waves.
  double w[NENT], tot = 0.0;
  for (int e=0;e<NENT;e++){
    Ent E = ent_of(e);
    w[e] = (double)((2*E.l1+1)*(2*E.lo+1) + 2*(2*E.lo+1));
    tot += w[e];
  }
  int ends[4]; double acc = 0.0; int c = 0;
  for (int e=0;e<NENT && c<3;e++){
    acc += w[e];
    if (acc >= tot*(c+1)/4.0){ ends[c++] = e+1; }
  }
  while (c<3) ends[c++] = NENT;
  ends[3] = NENT;
  int4 bnd = make_int4(ends[0], ends[1], ends[2], ends[3]);

  setup_kernel<<<NENT, 320, 0, stream>>>(ws);
  main_kernel<<<batch/EPB, TPB, 0, stream>>>(re, im, out, ws, bnd);
}

// Round 5
// 368.882 us; speedup vs baseline: 1.2679x; 1.1661x over previous
//
#include <hip/hip_runtime.h>
#include <utility>

#define LMAX 8
#define NENT 249
#define NPAIR 45
#define EPB 128            // batch elements per block (2 per lane, f32x2-packed)
#define TPB 512            // 8 waves
#define ESTR 130           // padded elem stride (floats)
#define NCO 45             // sum_{l<=8}(l+1)
#define PLANE (NCO*ESTR)
#define P1END 30           // pairs [0,30) have l1<=3  -> FULL ranks [0,100)
#define FSPLIT 100         // FULL-rank phase split
#define PSLOT 115          // POWER slots base (phase-2 FULL uses slots [0,115))
#define NSLOT 149          // total stage slots

typedef __attribute__((ext_vector_type(2))) float f32x2;

struct P2 { int l1, l2; };

__host__ __device__ constexpr int tri_(int l){ return l*(l+1)/2; }
// F_l^{m} for m<0 equals (sr*Re, sq*Im) of the stored value at |m| (m>=1 only;
// m=0 is a full complex value — NO reality constraint, see round-4 post-mortem).
__host__ __device__ constexpr int sr_(int m){ return m>=0 ? 1 : (((-m)&1)? -1 : 1); }
__host__ __device__ constexpr int sq_(int m){ return m>=0 ? 1 : (((-m)&1)? 1 : -1); }

__host__ __device__ constexpr P2 pair_of(int w){
  int n=0;
  for(int a=0;a<=LMAX;a++) for(int b=a;b<=LMAX;b++){ if(n==w) return P2{a,b}; n++; }
  return P2{0,0};
}

// index of (l1,l2,lo) in FULL_MAP generation order
__host__ __device__ constexpr int full_rank(int l1,int l2,int lo){
  int r=0;
  for(int a=0;a<=LMAX;a++) for(int b=a;b<=LMAX;b++){
    int hi=a+b>LMAX?LMAX:a+b;
    for(int c=b-a;c<=hi;c++){ if(a==l1&&b==l2&&c==lo) return r; r++; }
  }
  return -1;
}

// index of (l1,l2,lo) in POWER_MAP generation order; -1 if not a POWER entry
__host__ __device__ constexpr int power_idx(int l1,int l2,int lo){
  int n=0;
  for(int b=2;b<=LMAX;b++){
    if(l1==1&&l2==b&&lo==b-1) return n; n++;
    if(b>=4){ if(l1==1&&l2==b&&lo==b) return n; n++; }
  }
  for(int b=3;b<=LMAX;b++){
    if(l1==2&&l2==b&&lo==b-2) return n; n++;
    if(l1==2&&l2==b&&lo==b-1) return n; n++;
  }
  if(l1==3&&l2==3&&lo==2) return n; n++;
  for(int b=4;b<=LMAX;b++){
    if(l1==3&&l2==b&&lo==b-3) return n; n++;
    if((b&1)&&b>=5){
      if(l1==3&&l2==b&&lo==b-2) return n; n++;
      if(l1==3&&l2==b&&lo==b-1) return n; n++;
    }
  }
  return -1;
}

// ---- compile-time Clebsch-Gordan -------------------------------------------
__host__ __device__ constexpr double csqrt_(double x){
  if (x<=0.0) return 0.0;
  double v=x, s=1.0;
  while (v>4.0){ v*=0.25; s*=2.0; }
  while (v<0.25){ v*=4.0; s*=0.5; }
  double g=v;
  for(int i=0;i<48;i++) g=0.5*(g+v/g);
  return g*s;
}
__host__ __device__ constexpr double cgC(int j1,int m1,int j2,int m2,int j3,int m3){
  if (m1+m2 != m3) return 0.0;
  int dj=j1-j2; if(dj<0)dj=-dj;
  if (j3<dj || j3>j1+j2) return 0.0;
  if (m2<-j2 || m2>j2 || m1<-j1 || m1>j1 || m3<-j3 || m3>j3) return 0.0;
  double f[26]={}; f[0]=1.0;
  for(int t=1;t<26;t++) f[t]=f[t-1]*(double)t;
  double pre = csqrt_((2.0*j3+1.0)*f[j1+j2-j3]*f[j1-j2+j3]*f[-j1+j2+j3]/f[j1+j2+j3+1]);
  pre *= csqrt_(f[j1+m1]*f[j1-m1]*f[j2+m2]*f[j2-m2]*f[j3+m3]*f[j3-m3]);
  int kmin=0; if(j2-j3-m1>kmin)kmin=j2-j3-m1; if(j1-j3+m2>kmin)kmin=j1-j3+m2;
  int kmax=j1+j2-j3; if(j1-m1<kmax)kmax=j1-m1; if(j2+m2<kmax)kmax=j2+m2;
  double s=0.0;
  for(int k=kmin;k<=kmax;k++){
    double term = 1.0/(f[k]*f[j1+j2-j3-k]*f[j1-m1-k]*f[j2+m2-k]*f[j3-j2+m1+k]*f[j3-j1-m2+k]);
    s += (k&1)? -term : term;
  }
  return pre*s;
}

template<int L1,int L2>
struct CGTab {
  static constexpr int LOmx = (L1+L2<LMAX)?(L1+L2):LMAX;
  static constexpr int LOmn = L2-L1;
  static constexpr int NLO  = LOmx-LOmn+1;
  float c[NLO][2*LOmx+1][2*L1+1];   // [lo-LOmn][M+LOmx][m1+L1]
};
template<int L1,int L2>
__host__ __device__ constexpr CGTab<L1,L2> make_cgtab(){
  CGTab<L1,L2> T{};
  for(int lo=T.LOmn; lo<=T.LOmx; lo++)
    for(int M=-T.LOmx; M<=T.LOmx; M++)
      for(int m1=-L1;m1<=L1;m1++){
        double v=0.0;
        if (M>=-lo && M<=lo){
          int m2=M-m1;
          if(m2>=-L2&&m2<=L2) v = cgC(L1,m1,L2,m2,lo,M);
        }
        T.c[lo-T.LOmn][M+T.LOmx][m1+L1] = (float)v;
      }
  return T;
}

// ---- per-pair compute (FULL M range, no symmetry assumptions) --------------
// For each M in [-LOmax, LOmax]: products P_i = F1_{m1}*F2_{M-m1} once, then
// per-lo constexpr-CG dot; beta += Re(G_M conj(F3_M)); power += |G_M|^2.
template<int PI>
__device__ __attribute__((always_inline)) inline void do_pair(
    const float* __restrict__ lds, float* __restrict__ stage, int lane2)
{
  constexpr P2 pe = pair_of(PI);
  constexpr int L1 = pe.l1, L2 = pe.l2;
  constexpr int LOmin = L2-L1;
  constexpr int LOmax = (L1+L2<LMAX)?(L1+L2):LMAX;
  constexpr int NLO = LOmax-LOmin+1;
  constexpr int B1 = tri_(L1), B2 = tri_(L2);
  constexpr auto tab = make_cgtab<L1,L2>();

  // register-cache raw F1, F2 (|m| values; signs folded at compile time below)
  f32x2 X1[L1+1], Y1[L1+1], X2[L2+1], Y2[L2+1];
#pragma unroll
  for (int a=0;a<=L1;a++){
    X1[a] = *(const f32x2*)&lds[(B1+a)*ESTR + lane2];
    Y1[a] = *(const f32x2*)&lds[PLANE + (B1+a)*ESTR + lane2];
  }
#pragma unroll
  for (int a=0;a<=L2;a++){
    X2[a] = *(const f32x2*)&lds[(B2+a)*ESTR + lane2];
    Y2[a] = *(const f32x2*)&lds[PLANE + (B2+a)*ESTR + lane2];
  }

  f32x2 bAcc[NLO], pAcc[NLO];
#pragma unroll
  for (int t=0;t<NLO;t++){ bAcc[t]=f32x2{0.f,0.f}; pAcc[t]=f32x2{0.f,0.f}; }

#pragma unroll
  for (int M=-LOmax; M<=LOmax; M++){
    const int m1lo = (M-L2 > -L1) ? (M-L2) : -L1;
    const int m1hi = (M+L2 <  L1) ? (M+L2) :  L1;
    f32x2 Prd[2*L1+1], Pid[2*L1+1];
#pragma unroll
    for (int m1=-L1; m1<=L1; m1++){
      if (m1<m1lo || m1>m1hi) continue;     // folds after unroll
      const int i  = m1-m1lo;
      const int m2 = M-m1;
      const int a1 = m1<0?-m1:m1, a2 = m2<0?-m2:m2;
      const int s1 = sr_(m1)*sr_(m2);
      const int s2 = -(sq_(m1)*sq_(m2));
      const int s3 = sr_(m1)*sq_(m2);
      const int s4 = sq_(m1)*sr_(m2);
      f32x2 t1 = (s1>0? X1[a1] : -X1[a1]) * X2[a2];
      Prd[i] = __builtin_elementwise_fma((s2>0? Y1[a1] : -Y1[a1]), Y2[a2], t1);
      f32x2 t2 = (s3>0? X1[a1] : -X1[a1]) * Y2[a2];
      Pid[i] = __builtin_elementwise_fma((s4>0? Y1[a1] : -Y1[a1]), X2[a2], t2);
    }
#pragma unroll
    for (int lo=LOmin; lo<=LOmax; lo++){
      if (lo < (M<0?-M:M)) continue;        // G_M only exists for |M|<=lo
      f32x2 Gr = {0.f,0.f}, Gi = {0.f,0.f};
#pragma unroll
      for (int m1=-L1; m1<=L1; m1++){
        if (m1<m1lo || m1>m1hi) continue;
        const int i = m1-m1lo;
        const float C = tab.c[lo-LOmin][M+LOmax][m1+L1];
        if (C != 0.f){
          f32x2 Cv = {C,C};
          Gr = __builtin_elementwise_fma(Cv, Prd[i], Gr);
          Gi = __builtin_elementwise_fma(Cv, Pid[i], Gi);
        }
      }
      // beta += Re(G_M * conj(F3_M)); F3_M = (sr*x3, sq*y3) with x3,y3 at |M|
      const int aM = M<0?-M:M;
      const int B3 = tri_(lo);
      f32x2 x3 = *(const f32x2*)&lds[(B3+aM)*ESTR + lane2];
      f32x2 y3 = *(const f32x2*)&lds[PLANE + (B3+aM)*ESTR + lane2];
      const int AL = sr_(M), BE = sq_(M);   // fold after unroll
      bAcc[lo-LOmin] = __builtin_elementwise_fma(Gr, (AL>0? x3 : -x3), bAcc[lo-LOmin]);
      bAcc[lo-LOmin] = __builtin_elementwise_fma(Gi, (BE>0? y3 : -y3), bAcc[lo-LOmin]);
      if (power_idx(L1,L2,lo) >= 0){        // compile-time condition
        pAcc[lo-LOmin] = __builtin_elementwise_fma(Gr, Gr, pAcc[lo-LOmin]);
        pAcc[lo-LOmin] = __builtin_elementwise_fma(Gi, Gi, pAcc[lo-LOmin]);
      }
    }
  }

  // emit to LDS stage ([slot][elem]); pair-disjoint slots, no races
#pragma unroll
  for (int lo=LOmin; lo<=LOmax; lo++){
    const int fr   = full_rank(L1,L2,lo);
    const int slot = fr<FSPLIT ? fr : fr-FSPLIT;   // phase-1 pairs all have fr<100
    *(f32x2*)&stage[slot*ESTR + lane2] = bAcc[lo-LOmin];
    const int pidx = power_idx(L1,L2,lo);
    if (pidx>=0)
      *(f32x2*)&stage[(PSLOT+pidx)*ESTR + lane2] = pAcc[lo-LOmin];
  }
}

template<int PI>
__device__ __attribute__((always_inline)) inline void pair_step(
    const float* __restrict__ lds, float* __restrict__ stage, int lane2, int s, int e_)
{
  if (PI>=s && PI<e_) do_pair<PI>(lds, stage, lane2);   // wave-uniform
}
template<int OFF, int... Ps>
__device__ __attribute__((always_inline)) inline void pair_range(
    std::integer_sequence<int,Ps...>,
    const float* __restrict__ lds, float* __restrict__ stage, int lane2, int s, int e_)
{
  (pair_step<OFF+Ps>(lds, stage, lane2, s, e_), ...);
}

struct Bnd { int e1[8]; int e2[8]; };

constexpr int LDS_FLOATS = 2*PLANE + NSLOT*ESTR;
constexpr int LDS_BYTES  = LDS_FLOATS*4;   // 124,280 B
static_assert(LDS_BYTES <= 160*1024, "LDS over 160KB");

__global__ __launch_bounds__(TPB, 2) void main_kernel(
    const float* __restrict__ re, const float* __restrict__ im,
    float* __restrict__ out, Bnd bnd)
{
  extern __shared__ float lds[];
  float* stage = lds + 2*PLANE;
  const int gbase = blockIdx.x*EPB;

  // stage the m<=l triangle of 128 elements into [coeff][elem] planes
  for (int t=threadIdx.x; t<EPB*81; t+=TPB){
    float vr = re[(size_t)gbase*81 + t];
    float vi = im[(size_t)gbase*81 + t];
    int elem = t/81, x = t - elem*81;
    int l = x/9, m = x - l*9;
    if (m<=l){
      int off = tri_(l)+m;
      lds[off*ESTR+elem] = vr;
      lds[PLANE + off*ESTR+elem] = vi;
    }
  }
  __syncthreads();

  const int lane  = threadIdx.x & 63;
  const int wv    = __builtin_amdgcn_readfirstlane(threadIdx.x >> 6);
  const int lane2 = lane*2;
  const int s1 = (wv==0)? 0      : bnd.e1[wv-1];
  const int E1 = bnd.e1[wv];
  const int s2 = (wv==0)? P1END  : bnd.e2[wv-1];
  const int E2 = bnd.e2[wv];
  const long long obase = (long long)gbase*NENT;

  // phase 1: pairs with l1<=3 (FULL ranks [0,100) + all POWER slots)
  pair_range<0>(std::make_integer_sequence<int,P1END>{}, lds, stage, lane2, s1, E1);
  __syncthreads();

  // flush A: out entries [0,100) per element (coalesced 400B runs)
  for (int p=threadIdx.x; p<EPB*FSPLIT; p+=TPB){
    int elem = p/FSPLIT, o = p - elem*FSPLIT;
    out[obase + (long long)elem*NENT + o] = stage[o*ESTR + elem];
  }
  __syncthreads();

  // phase 2: pairs with l1>=4 (FULL ranks [100,215) -> slots [0,115))
  pair_range<P1END>(std::make_integer_sequence<int,NPAIR-P1END>{}, lds, stage, lane2, s2, E2);
  __syncthreads();

  // flush B: out entries [100,249) <- slots [0,149) (coalesced 596B runs)
  for (int p=threadIdx.x; p<EPB*NSLOT; p+=TPB){
    int elem = p/NSLOT, o = p - elem*NSLOT;
    out[obase + (long long)elem*NENT + FSPLIT + o] = stage[o*ESTR + elem];
  }
}

extern "C" void kernel_launch(void* const* d_in, const int* in_sizes, int n_in,
                              void* d_out, int out_size, void* d_ws, size_t ws_size,
                              hipStream_t stream) {
  const float* re = (const float*)d_in[0];
  const float* im = (const float*)d_in[1];
  float* out = (float*)d_out;
  const int batch = in_sizes[0] / 81;

  hipFuncSetAttribute((const void*)main_kernel,
                      hipFuncAttributeMaxDynamicSharedMemorySize, LDS_BYTES);

  // per-pair cost model (pk-ops) for the 8-way per-phase wave balance
  double w[NPAIR];
  for (int p=0;p<NPAIR;p++){
    P2 pe = pair_of(p);
    int L1=pe.l1, L2=pe.l2;
    int LOmx=(L1+L2<LMAX)?(L1+L2):LMAX, LOmn=L2-L1;
    double ww = 2.0*(L1+L2+2);
    for (int M=-LOmx;M<=LOmx;M++){
      int lo_ = (M-L2>-L1)?(M-L2):-L1, hi_ = (M+L2<L1)?(M+L2):L1;
      int dn = hi_-lo_+1;
      ww += 4.0*dn;
      int aM = M<0?-M:M;
      for (int lo=(LOmn>aM?LOmn:aM); lo<=LOmx; lo++)
        ww += 2.0*dn + 2.0 + (power_idx(L1,L2,lo)>=0 ? 2.0 : 0.0);
    }
    w[p]=ww;
  }
  Bnd bnd;
  {  // phase 1: pairs [0, P1END)
    double tot=0; for(int p=0;p<P1END;p++) tot+=w[p];
    double acc=0; int c=0;
    for(int p=0;p<P1END && c<7;p++){ acc+=w[p]; if(acc>=tot*(c+1)/8.0) bnd.e1[c++]=p+1; }
    while(c<7) bnd.e1[c++]=P1END;
    bnd.e1[7]=P1END;
  }
  {  // phase 2: pairs [P1END, NPAIR)
    double tot=0; for(int p=P1END;p<NPAIR;p++) tot+=w[p];
    double acc=0; int c=0;
    for(int p=P1END;p<NPAIR && c<7;p++){ acc+=w[p]; if(acc>=tot*(c+1)/8.0) bnd.e2[c++]=p+1; }
    while(c<7) bnd.e2[c++]=NPAIR;
    bnd.e2[7]=NPAIR;
  }

  main_kernel<<<batch/EPB, TPB, LDS_BYTES, stream>>>(re, im, out, bnd);
}